// Round 12
// baseline (1942.587 us; speedup 1.0000x reference)
//
#include <hip/hip_runtime.h>
#include <hip/hip_fp16.h>

#define HID 64
#define ELLK 32   // slots/node; kept degree ~Poisson(5.5), max over 100k ~18
#define CUT_D2 132.5471f   // drop rbf < 1e-5 (R10: measured no absmax change)
#define NBLK 1008 // persistent grid: capacity 256CU x 4blk/CU = 1024, margin 16

typedef _Float16 half8 __attribute__((ext_vector_type(8)));
typedef float f32x4 __attribute__((ext_vector_type(4)));

__device__ __forceinline__ float rbf_of(unsigned w) {
    return __half2float(__ushort_as_half((unsigned short)(w & 0x7fff)));
}

// x16[n][h] = fp16(emb[z[n]][h]); zeroes ELL counters AND the global barrier.
__global__ void embed_kernel(const int* __restrict__ z, const float* __restrict__ emb,
                             __half* __restrict__ x16, int* __restrict__ cnt,
                             int* __restrict__ bar, int n) {
    int t = blockIdx.x * blockDim.x + threadIdx.x;
    if (t == 0) *bar = 0;              // re-zeroed every graph replay
    if (t <= n) cnt[t] = 0;
    if (t >= n * HID / 2) return;
    int node = t >> 5, h2 = (t & 31) * 2;
    const float* src = emb + z[node] * HID + h2;
    __half2 v;
    v.x = __float2half(src[0]);
    v.y = __float2half(src[1]);
    *(__half2*)(x16 + (size_t)node * HID + h2) = v;
}

// Software global barrier (R29): requires ALL NBLK blocks co-resident —
// guaranteed by launch_bounds(512,8) => VGPR<=64 => 4 blk/CU (32 waves),
// LDS 16KB*4=64KB<=160KB, NBLK=1008 <= 1024 capacity. Monotonic counter,
// zeroed by embed each iteration; AGENT-scope release/acquire per G16.
__device__ __forceinline__ void gbar(int* bar, int target) {
    __threadfence();                   // prior writes visible device-wide
    __syncthreads();                   // whole block done with the phase
    if (threadIdx.x == 0) {
        __hip_atomic_fetch_add(bar, 1, __ATOMIC_ACQ_REL, __HIP_MEMORY_SCOPE_AGENT);
        while (__hip_atomic_load(bar, __ATOMIC_ACQUIRE, __HIP_MEMORY_SCOPE_AGENT) < target)
            __builtin_amdgcn_s_sleep(2);
    }
    __syncthreads();                   // block waits on thread 0's acquire
}

// R29: MEGA-KERNEL — fill + 3 fused layers in ONE dispatch (was 4).
// R28 post-mortem: one-tile-per-wave regressed (16 in-flight half8 dests = 64
// VGPRs over budget; serial MFMA tail). Layer body reverted to R27 VERBATIM
// (R24/R26/R27/R28 all confirm it's at its structural floor ~36us). The
// remaining untouched term is ~44-60us of dispatch gaps -> persistent kernel:
//   phase 0: grid-stride fill (1M edges, 2 iters)  -> gbar
//   per layer: W->LDS (+syncthreads), grid-stride tile-groups running the
//   R27 gather/syncthreads/mfma body, trailing syncthreads (ltile reuse);
//   gbar between layers (not after the last).
// Math identical to R27 -> bit-identical output (absmax 0.00390625).
__global__ void __launch_bounds__(512, 8)
mega_kernel(const int* __restrict__ erow, const int* __restrict__ ecol,
            const float* __restrict__ pos, int* __restrict__ cnt,
            unsigned* __restrict__ ell, __half* __restrict__ X16,
            __half* __restrict__ Y16, const float* __restrict__ Ws,
            const float* __restrict__ bs, float* __restrict__ out,
            int* __restrict__ bar, int n, int e, int nlayers) {
    __shared__ __align__(16) __half ltile[4][16 * HID];   // 8KB: 4 tiles
    __shared__ __align__(16) __half wlds[8][64][8];       // 8KB: [frag][lane][8]
    int tid = threadIdx.x;
    int lane = tid & 63;
    int wv = tid >> 6;                 // wave 0..7

    int grp = lane >> 3;               // gather: group = node within the pack
    int gl  = lane & 7;                // gather: lane within group = h-chunk
    int r16 = lane & 15;               // mfma: A row / out col
    int quad = lane >> 4;              // mfma: k-chunk / out row group

    // ================= phase 0: ELL fill (R27 fill body, grid-stride) =========
    for (int t = blockIdx.x * blockDim.x + tid; t < e; t += NBLK * 512) {
        int r = erow[t], c = ecol[t];
        float dx = pos[3 * r]     - pos[3 * c];
        float dy = pos[3 * r + 1] - pos[3 * c + 1];
        float dz = pos[3 * r + 2] - pos[3 * c + 2];
        float d2 = dx * dx + dy * dy + dz * dz;
        if (d2 > CUT_D2) continue;
        float rbf = expf(-sqrtf(d2));
        unsigned short hb = __half_as_ushort(__float2half(rbf));
        int p = atomicAdd(&cnt[r], 1);
        if (p < ELLK) ell[(size_t)r * ELLK + p] = ((unsigned)c << 15) | (unsigned)hb;
    }
    gbar(bar, NBLK);                   // fill complete device-wide

    int ntiles = (n + 15) >> 4;
    int ngroups = (ntiles + 3) >> 2;   // 4 tiles per group

    for (int l = 0; l < nlayers; ++l) {
        bool last = (l == nlayers - 1);
        const __half* x16 = (l & 1) ? Y16 : X16;
        __half* out16 = last ? (__half*)0 : ((l & 1) ? X16 : Y16);
        float* out32 = last ? out : (float*)0;
        const float* W = Ws + (size_t)l * HID * HID;
        const float* b = bs + (size_t)l * HID;

        // ---- W -> LDS preload (512 threads, 512 frag-slots, 1 each) ----
        {
            int f = tid >> 6, ll = tid & 63;
            int ht = f >> 1, kt = f & 1, q = ll >> 4, r = ll & 15;
            const float* src = W + (ht * 16 + r) * HID + kt * 32 + q * 8;
            half8 h;
#pragma unroll
            for (int j = 0; j < 8; ++j) h[j] = (_Float16)src[j];
            *(half8*)&wlds[f][ll][0] = h;
        }
        float biasv[4];
#pragma unroll
        for (int ht = 0; ht < 4; ++ht) biasv[ht] = b[ht * 16 + r16];
        __syncthreads();

        for (int g = blockIdx.x; g < ngroups; g += NBLK) {
            int Tb = g << 2;           // first tile of this group

            // ====== gather: one 8-node pack per wave (R27 verbatim) ======
            {
                int n8 = (Tb << 4) + (wv << 3);
                int own = n8 + grp; if (own >= n) own = n - 1;  // clamp (loads)

                int cn = n8 + (lane & 7);
                int myc = cnt[cn < n ? cn : n - 1];
                if (cn >= n) myc = 0;
                if (myc > ELLK) myc = ELLK;

                unsigned rec[4];
#pragma unroll
                for (int r = 0; r < 4; ++r)
                    rec[r] = ell[(size_t)own * ELLK + r * 8 + gl];

                half8 res = *(const half8*)(x16 + (size_t)own * HID + gl * 8);

                int c_own = __shfl(myc, grp);          // uniform within group
#pragma unroll
                for (int r = 0; r < 4; ++r)
                    if (r * 8 + gl >= c_own) rec[r] = (unsigned)own << 15;

                float acc[8];
#pragma unroll
                for (int k = 0; k < 8; ++k) acc[k] = (float)res[k];

#pragma unroll
                for (int r = 0; r < 4; ++r) {
                    if (8 * r < c_own) {               // group-uniform octet guard
#pragma unroll
                        for (int i = 0; i < 8; ++i) {
                            unsigned w = __shfl(rec[r], (lane & 56) + i);
                            half8 v = *(const half8*)(x16 + (size_t)(w >> 15) * HID + gl * 8);
                            float f = rbf_of(w);       // pre-masked: 0 if dead
#pragma unroll
                            for (int k = 0; k < 8; ++k)
                                acc[k] = fmaf((float)v[k], f, acc[k]);
                        }
                    }
                }

                half8 o;
#pragma unroll
                for (int k = 0; k < 8; ++k) o[k] = (_Float16)acc[k];
                char* tile = (char*)&ltile[wv >> 1][0];
                int ni = ((wv & 1) << 3) + grp;
                *(half8*)(tile + ni * 128 + ((gl << 4) ^ ((ni & 7) << 4))) = o;
            }
            __syncthreads();

            // ====== mfma: wave w -> tile (w&3), ht-half (w>>2) (R27 verbatim) ==
            {
                int tw = wv & 3;
                int t = Tb + tw;
                if (t < ntiles) {
                    int tbase = t << 4;
                    char* tile = (char*)&ltile[tw][0];
                    const half8* wl = (const half8*)&wlds[0][0][0];
                    half8 afrag0 = *(const half8*)(tile + r16 * 128 + ((quad << 4) ^ ((r16 & 7) << 4)));
                    half8 afrag1 = *(const half8*)(tile + r16 * 128 + (((quad + 4) << 4) ^ ((r16 & 7) << 4)));
                    int htb = (wv >> 2) << 1;          // 0 or 2
#pragma unroll
                    for (int hh = 0; hh < 2; ++hh) {
                        int ht = htb + hh;
                        f32x4 acc = {biasv[ht], biasv[ht], biasv[ht], biasv[ht]};
                        half8 b0 = wl[(ht * 2 + 0) * 64 + lane];
                        half8 b1 = wl[(ht * 2 + 1) * 64 + lane];
                        acc = __builtin_amdgcn_mfma_f32_16x16x32_f16(afrag0, b0, acc, 0, 0, 0);
                        acc = __builtin_amdgcn_mfma_f32_16x16x32_f16(afrag1, b1, acc, 0, 0, 0);
#pragma unroll
                        for (int r = 0; r < 4; ++r) {
                            int row = tbase + quad * 4 + r;
                            if (row < n) {
                                float v = fmaxf(acc[r], 0.0f);
                                size_t idx = (size_t)row * HID + ht * 16 + r16;
                                if (out32) out32[idx] = v;
                                if (out16) out16[idx] = __float2half(v);
                            }
                        }
                    }
                }
            }
            __syncthreads();           // ltile reused by next group iteration
        }
        if (!last) gbar(bar, NBLK * (2 + l));   // layer outputs visible device-wide
    }
}

extern "C" void kernel_launch(void* const* d_in, const int* in_sizes, int n_in,
                              void* d_out, int out_size, void* d_ws, size_t ws_size,
                              hipStream_t stream) {
    const int*   z    = (const int*)d_in[0];
    const float* pos  = (const float*)d_in[1];
    const int*   eidx = (const int*)d_in[2];
    const float* emb  = (const float*)d_in[3];
    const float* Ws   = (const float*)d_in[4];
    const float* bs   = (const float*)d_in[5];
    int n = in_sizes[0];
    int e = in_sizes[2] / 2;
    int nlayers = in_sizes[4] / (HID * HID);
    const int* row = eidx;
    const int* col = eidx + e;
    float* out = (float*)d_out;

    char* ws = (char*)d_ws;
    __half*   X16 = (__half*)ws;                                   // n*64 fp16 (12.8 MB)
    __half*   Y16 = X16 + (size_t)n * HID;                         // n*64 fp16 (ping-pong)
    unsigned* ell = (unsigned*)((char*)Y16 + (size_t)n * HID * 2); // (n+2)*ELLK u32
    int*      cnt = (int*)((char*)ell + (size_t)(n + 2) * ELLK * 4); // n+1 ints
    int*      bar = cnt + (n + 2);                                 // barrier counter

    // 2 dispatches: embed(+cnt/bar zero), mega(fill + 3 layers, spin barriers)
    embed_kernel<<<(n * HID / 2 + 255) / 256, 256, 0, stream>>>(z, emb, X16, cnt, bar, n);
    mega_kernel<<<NBLK, 512, 0, stream>>>(row, col, pos, cnt, ell, X16, Y16,
                                          Ws, bs, out, bar, n, e, nlayers);
}

// Round 13
// 662.944 us; speedup vs baseline: 2.9302x; 2.9302x over previous
//
#include <hip/hip_runtime.h>
#include <hip/hip_fp16.h>

#define HID 64
#define ELLK 32   // slots/node; kept degree ~Poisson(5.5), max over 100k ~18
#define CUT_D2 132.5471f   // drop rbf < 1e-5 (R10: measured no absmax change)
#define NBLK 504  // guaranteed co-resident: launch_bounds(512,4) => VGPR<=128
                  // => >=16 waves/CU => >=2 blocks/CU x 256 CU = 512 >= 504.

typedef _Float16 half8 __attribute__((ext_vector_type(8)));
typedef float f32x4 __attribute__((ext_vector_type(4)));

__device__ __forceinline__ float rbf_of(unsigned w) {
    return __half2float(__ushort_as_half((unsigned short)(w & 0x7fff)));
}

// x16[n][h] = fp16(emb[z[n]][h]); zeroes ELL counters AND the global barrier.
__global__ void embed_kernel(const int* __restrict__ z, const float* __restrict__ emb,
                             __half* __restrict__ x16, int* __restrict__ cnt,
                             int* __restrict__ bar, int n) {
    int t = blockIdx.x * blockDim.x + threadIdx.x;
    if (t == 0) *bar = 0;              // re-zeroed every graph replay
    if (t <= n) cnt[t] = 0;
    if (t >= n * HID / 2) return;
    int node = t >> 5, h2 = (t & 31) * 2;
    const float* src = emb + z[node] * HID + h2;
    __half2 v;
    v.x = __float2half(src[0]);
    v.y = __float2half(src[1]);
    *(__half2*)(x16 + (size_t)node * HID + h2) = v;
}

// Software global barrier (R29-proven correct incl. cross-XCD visibility:
// R29 PASSED with bit-identical output). Monotonic counter, zeroed by embed
// each replay; AGENT-scope release/acquire per G16.
__device__ __forceinline__ void gbar(int* bar, int target) {
    __threadfence();                   // prior writes visible device-wide
    __syncthreads();                   // whole block done with the phase
    if (threadIdx.x == 0) {
        __hip_atomic_fetch_add(bar, 1, __ATOMIC_ACQ_REL, __HIP_MEMORY_SCOPE_AGENT);
        while (__hip_atomic_load(bar, __ATOMIC_ACQUIRE, __HIP_MEMORY_SCOPE_AGENT) < target)
            __builtin_amdgcn_s_sleep(2);
    }
    __syncthreads();                   // block waits on thread 0's acquire
}

// R30: R29 mega-kernel with the VGPR fix.
// R29 post-mortem: launch_bounds(512,8) forced VGPR_Count=32 -> the R27 body
// spilled ~1.1GB/dispatch (FETCH 564MB + WRITE 577MB), 1943us. Structure and
// barrier logic were CORRECT (passed, absmax bit-identical).
// R30 deltas: (1) launch_bounds(512,4): VGPR cap 128, allocator's empirical
// target 64 (6 builds) -> no spill; (2) NBLK=504: co-residency guaranteed by
// the bound's own worst case (VGPR<=128 => >=2 blocks/CU => capacity >=512),
// so NO hang mode exists; 16 waves/CU >= R25's achieved ~10. Layer body =
// R27 VERBATIM. Math identical -> bit-identical output (absmax 0.00390625).
__global__ void __launch_bounds__(512, 4)
mega_kernel(const int* __restrict__ erow, const int* __restrict__ ecol,
            const float* __restrict__ pos, int* __restrict__ cnt,
            unsigned* __restrict__ ell, __half* __restrict__ X16,
            __half* __restrict__ Y16, const float* __restrict__ Ws,
            const float* __restrict__ bs, float* __restrict__ out,
            int* __restrict__ bar, int n, int e, int nlayers) {
    __shared__ __align__(16) __half ltile[4][16 * HID];   // 8KB: 4 tiles
    __shared__ __align__(16) __half wlds[8][64][8];       // 8KB: [frag][lane][8]
    int tid = threadIdx.x;
    int lane = tid & 63;
    int wv = tid >> 6;                 // wave 0..7

    int grp = lane >> 3;               // gather: group = node within the pack
    int gl  = lane & 7;                // gather: lane within group = h-chunk
    int r16 = lane & 15;               // mfma: A row / out col
    int quad = lane >> 4;              // mfma: k-chunk / out row group

    // ================= phase 0: ELL fill (grid-stride) =========
    for (int t = blockIdx.x * blockDim.x + tid; t < e; t += NBLK * 512) {
        int r = erow[t], c = ecol[t];
        float dx = pos[3 * r]     - pos[3 * c];
        float dy = pos[3 * r + 1] - pos[3 * c + 1];
        float dz = pos[3 * r + 2] - pos[3 * c + 2];
        float d2 = dx * dx + dy * dy + dz * dz;
        if (d2 > CUT_D2) continue;
        float rbf = expf(-sqrtf(d2));
        unsigned short hb = __half_as_ushort(__float2half(rbf));
        int p = atomicAdd(&cnt[r], 1);
        if (p < ELLK) ell[(size_t)r * ELLK + p] = ((unsigned)c << 15) | (unsigned)hb;
    }
    gbar(bar, NBLK);                   // fill complete device-wide

    int ntiles = (n + 15) >> 4;
    int ngroups = (ntiles + 3) >> 2;   // 4 tiles per group

    for (int l = 0; l < nlayers; ++l) {
        bool last = (l == nlayers - 1);
        const __half* x16 = (l & 1) ? Y16 : X16;
        __half* out16 = last ? (__half*)0 : ((l & 1) ? X16 : Y16);
        float* out32 = last ? out : (float*)0;
        const float* W = Ws + (size_t)l * HID * HID;
        const float* b = bs + (size_t)l * HID;

        // ---- W -> LDS preload (512 threads, 512 frag-slots, 1 each) ----
        {
            int f = tid >> 6, ll = tid & 63;
            int ht = f >> 1, kt = f & 1, q = ll >> 4, r = ll & 15;
            const float* src = W + (ht * 16 + r) * HID + kt * 32 + q * 8;
            half8 h;
#pragma unroll
            for (int j = 0; j < 8; ++j) h[j] = (_Float16)src[j];
            *(half8*)&wlds[f][ll][0] = h;
        }
        float biasv[4];
#pragma unroll
        for (int ht = 0; ht < 4; ++ht) biasv[ht] = b[ht * 16 + r16];
        __syncthreads();

        for (int g = blockIdx.x; g < ngroups; g += NBLK) {
            int Tb = g << 2;           // first tile of this group

            // ====== gather: one 8-node pack per wave (R27 verbatim) ======
            {
                int n8 = (Tb << 4) + (wv << 3);
                int own = n8 + grp; if (own >= n) own = n - 1;  // clamp (loads)

                int cn = n8 + (lane & 7);
                int myc = cnt[cn < n ? cn : n - 1];
                if (cn >= n) myc = 0;
                if (myc > ELLK) myc = ELLK;

                unsigned rec[4];
#pragma unroll
                for (int r = 0; r < 4; ++r)
                    rec[r] = ell[(size_t)own * ELLK + r * 8 + gl];

                half8 res = *(const half8*)(x16 + (size_t)own * HID + gl * 8);

                int c_own = __shfl(myc, grp);          // uniform within group
#pragma unroll
                for (int r = 0; r < 4; ++r)
                    if (r * 8 + gl >= c_own) rec[r] = (unsigned)own << 15;

                float acc[8];
#pragma unroll
                for (int k = 0; k < 8; ++k) acc[k] = (float)res[k];

#pragma unroll
                for (int r = 0; r < 4; ++r) {
                    if (8 * r < c_own) {               // group-uniform octet guard
#pragma unroll
                        for (int i = 0; i < 8; ++i) {
                            unsigned w = __shfl(rec[r], (lane & 56) + i);
                            half8 v = *(const half8*)(x16 + (size_t)(w >> 15) * HID + gl * 8);
                            float f = rbf_of(w);       // pre-masked: 0 if dead
#pragma unroll
                            for (int k = 0; k < 8; ++k)
                                acc[k] = fmaf((float)v[k], f, acc[k]);
                        }
                    }
                }

                half8 o;
#pragma unroll
                for (int k = 0; k < 8; ++k) o[k] = (_Float16)acc[k];
                char* tile = (char*)&ltile[wv >> 1][0];
                int ni = ((wv & 1) << 3) + grp;
                *(half8*)(tile + ni * 128 + ((gl << 4) ^ ((ni & 7) << 4))) = o;
            }
            __syncthreads();

            // ====== mfma: wave w -> tile (w&3), ht-half (w>>2) (R27 verbatim) ==
            {
                int tw = wv & 3;
                int t = Tb + tw;
                if (t < ntiles) {
                    int tbase = t << 4;
                    char* tile = (char*)&ltile[tw][0];
                    const half8* wl = (const half8*)&wlds[0][0][0];
                    half8 afrag0 = *(const half8*)(tile + r16 * 128 + ((quad << 4) ^ ((r16 & 7) << 4)));
                    half8 afrag1 = *(const half8*)(tile + r16 * 128 + (((quad + 4) << 4) ^ ((r16 & 7) << 4)));
                    int htb = (wv >> 2) << 1;          // 0 or 2
#pragma unroll
                    for (int hh = 0; hh < 2; ++hh) {
                        int ht = htb + hh;
                        f32x4 acc = {biasv[ht], biasv[ht], biasv[ht], biasv[ht]};
                        half8 b0 = wl[(ht * 2 + 0) * 64 + lane];
                        half8 b1 = wl[(ht * 2 + 1) * 64 + lane];
                        acc = __builtin_amdgcn_mfma_f32_16x16x32_f16(afrag0, b0, acc, 0, 0, 0);
                        acc = __builtin_amdgcn_mfma_f32_16x16x32_f16(afrag1, b1, acc, 0, 0, 0);
#pragma unroll
                        for (int r = 0; r < 4; ++r) {
                            int row = tbase + quad * 4 + r;
                            if (row < n) {
                                float v = fmaxf(acc[r], 0.0f);
                                size_t idx = (size_t)row * HID + ht * 16 + r16;
                                if (out32) out32[idx] = v;
                                if (out16) out16[idx] = __float2half(v);
                            }
                        }
                    }
                }
            }
            __syncthreads();           // ltile reused by next group iteration
        }
        if (!last) gbar(bar, NBLK * (2 + l));   // layer outputs visible device-wide
    }
}

extern "C" void kernel_launch(void* const* d_in, const int* in_sizes, int n_in,
                              void* d_out, int out_size, void* d_ws, size_t ws_size,
                              hipStream_t stream) {
    const int*   z    = (const int*)d_in[0];
    const float* pos  = (const float*)d_in[1];
    const int*   eidx = (const int*)d_in[2];
    const float* emb  = (const float*)d_in[3];
    const float* Ws   = (const float*)d_in[4];
    const float* bs   = (const float*)d_in[5];
    int n = in_sizes[0];
    int e = in_sizes[2] / 2;
    int nlayers = in_sizes[4] / (HID * HID);
    const int* row = eidx;
    const int* col = eidx + e;
    float* out = (float*)d_out;

    char* ws = (char*)d_ws;
    __half*   X16 = (__half*)ws;                                   // n*64 fp16 (12.8 MB)
    __half*   Y16 = X16 + (size_t)n * HID;                         // n*64 fp16 (ping-pong)
    unsigned* ell = (unsigned*)((char*)Y16 + (size_t)n * HID * 2); // (n+2)*ELLK u32
    int*      cnt = (int*)((char*)ell + (size_t)(n + 2) * ELLK * 4); // n+1 ints
    int*      bar = cnt + (n + 2);                                 // barrier counter

    // 2 dispatches: embed(+cnt/bar zero), mega(fill + 3 layers, spin barriers)
    embed_kernel<<<(n * HID / 2 + 255) / 256, 256, 0, stream>>>(z, emb, X16, cnt, bar, n);
    mega_kernel<<<NBLK, 512, 0, stream>>>(row, col, pos, cnt, ell, X16, Y16,
                                          Ws, bs, out, bar, n, e, nlayers);
}

// Round 14
// 176.957 us; speedup vs baseline: 10.9777x; 3.7464x over previous
//
#include <hip/hip_runtime.h>
#include <hip/hip_fp16.h>

#define HID 64
#define ELLK 32   // slots/node; kept degree ~Poisson(5.5), max over 100k ~18
#define CUT_D2 132.5471f   // drop rbf < 1e-5 (R10: measured no absmax change)

typedef _Float16 half8 __attribute__((ext_vector_type(8)));
typedef float f32x4 __attribute__((ext_vector_type(4)));

__device__ __forceinline__ float rbf_of(unsigned w) {
    return __half2float(__ushort_as_half((unsigned short)(w & 0x7fff)));
}

// x16[n][h] = fp16(emb[z[n]][h]); zeroes ELL counters; packs pos4 (R31).
__global__ void embed_kernel(const int* __restrict__ z, const float* __restrict__ emb,
                             const float* __restrict__ pos, float4* __restrict__ pos4,
                             __half* __restrict__ x16, int* __restrict__ cnt, int n) {
    int t = blockIdx.x * blockDim.x + threadIdx.x;
    if (t <= n) cnt[t] = 0;
    if (t < n) {                       // pos -> pos4 (single-line 16B records)
        float4 p;
        p.x = pos[3 * t];
        p.y = pos[3 * t + 1];
        p.z = pos[3 * t + 2];
        p.w = 0.f;
        pos4[t] = p;
    }
    if (t >= n * HID / 2) return;
    int node = t >> 5, h2 = (t & 31) * 2;
    const float* src = emb + z[node] * HID + h2;
    __half2 v;
    v.x = __float2half(src[0]);
    v.y = __float2half(src[1]);
    *(__half2*)(x16 + (size_t)node * HID + h2) = v;
}

// ELL fill + fused rbf for KEPT edges; packed record (col<<15)|fp16(rbf).
// R31: pos4 loads — 2 single-line dwordx4 requests/edge instead of 6 scalar
// dwords (3x fewer random TA requests). Same f32 values -> d2/rbf bit-identical.
__global__ void fill_kernel(const int* __restrict__ row, const int* __restrict__ col,
                            const float4* __restrict__ pos4, int* __restrict__ cnt,
                            unsigned* __restrict__ ell, int e) {
    int t = blockIdx.x * blockDim.x + threadIdx.x;
    if (t >= e) return;
    int r = row[t], c = col[t];
    float4 pr = pos4[r];
    float4 pc = pos4[c];
    float dx = pr.x - pc.x;
    float dy = pr.y - pc.y;
    float dz = pr.z - pc.z;
    float d2 = dx * dx + dy * dy + dz * dz;
    if (d2 > CUT_D2) return;
    float rbf = expf(-sqrtf(d2));
    unsigned short hb = __half_as_ushort(__float2half(rbf));
    int p = atomicAdd(&cnt[r], 1);
    if (p < ELLK) ell[(size_t)r * ELLK + p] = ((unsigned)c << 15) | (unsigned)hb;
}

// R27 layer (champion, 176.2us): wave-specialized fused gather+linear.
// Post-R30 verdict: persistent mega-kernels are dead (R29: guaranteed-4-blk
// bounds force VGPR 32 -> 1.1GB spills; R30: guaranteed-2-blk gives too little
// TLP and kills cross-block pipelining -> 200us/layer). The 1563-block launch
// is what hides gather latency: fresh blocks start gathering while older
// blocks MFMA/drain. Layer body at its 4x-confirmed structural floor
// (R24 instr count, R26 predication, R27 requests, R28 barrier removal).
__global__ void __launch_bounds__(512)
layer_kernel(const __half* __restrict__ x16, const int* __restrict__ cnt,
             const unsigned* __restrict__ ell,
             const float* __restrict__ W, const float* __restrict__ b,
             float* __restrict__ out32, __half* __restrict__ out16, int n) {
    __shared__ __align__(16) __half ltile[4][16 * HID];   // 8KB: 4 tiles
    __shared__ __align__(16) __half wlds[8][64][8];       // 8KB: [frag][lane][8 halves]
    int tid = threadIdx.x;
    int lane = tid & 63;
    int wv = tid >> 6;                 // wave 0..7

    int grp = lane >> 3;               // gather: group = node within the pack
    int gl  = lane & 7;                // gather: lane within group = h-chunk
    int r16 = lane & 15;               // mfma: A row / out col
    int quad = lane >> 4;              // mfma: k-chunk / out row group

    // ---- W -> LDS preload (512 threads, 512 frag-slots, 1 each) ----
    {
        int f = tid >> 6, l = tid & 63;
        int ht = f >> 1, kt = f & 1, q = l >> 4, r = l & 15;
        const float* src = W + (ht * 16 + r) * HID + kt * 32 + q * 8;
        half8 h;
#pragma unroll
        for (int j = 0; j < 8; ++j) h[j] = (_Float16)src[j];
        *(half8*)&wlds[f][l][0] = h;
    }
    float biasv[4];
#pragma unroll
    for (int ht = 0; ht < 4; ++ht) biasv[ht] = b[ht * 16 + r16];
    __syncthreads();

    int ntiles = (n + 15) >> 4;
    int Tb = blockIdx.x << 2;          // first tile of this block

    // ================= gather phase: one 8-node pack per wave =================
    {
        int n8 = (Tb << 4) + (wv << 3);                    // pack base node
        int own = n8 + grp; if (own >= n) own = n - 1;     // clamp (loads only)

        int cn = n8 + (lane & 7);
        int myc = cnt[cn < n ? cn : n - 1];
        if (cn >= n) myc = 0;
        if (myc > ELLK) myc = ELLK;

        unsigned rec[4];
#pragma unroll
        for (int r = 0; r < 4; ++r)
            rec[r] = ell[(size_t)own * ELLK + r * 8 + gl];

        half8 res = *(const half8*)(x16 + (size_t)own * HID + gl * 8);

        int c_own = __shfl(myc, grp);                      // uniform within group
#pragma unroll
        for (int r = 0; r < 4; ++r)
            if (r * 8 + gl >= c_own) rec[r] = (unsigned)own << 15;  // rbf=0 no-op

        float acc[8];
#pragma unroll
        for (int k = 0; k < 8; ++k) acc[k] = (float)res[k];

#pragma unroll
        for (int r = 0; r < 4; ++r) {
            if (8 * r < c_own) {                       // group-uniform octet guard
#pragma unroll
                for (int i = 0; i < 8; ++i) {
                    unsigned w = __shfl(rec[r], (lane & 56) + i);
                    half8 v = *(const half8*)(x16 + (size_t)(w >> 15) * HID + gl * 8);
                    float f = rbf_of(w);               // pre-masked: 0 if dead
#pragma unroll
                    for (int k = 0; k < 8; ++k)
                        acc[k] = fmaf((float)v[k], f, acc[k]);
                }
            }
        }

        half8 o;
#pragma unroll
        for (int k = 0; k < 8; ++k) o[k] = (_Float16)acc[k];
        // wave wv -> tile wv/2, rows (wv&1)*8+grp; swizzled (R23 layout)
        char* tile = (char*)&ltile[wv >> 1][0];
        int ni = ((wv & 1) << 3) + grp;
        *(half8*)(tile + ni * 128 + ((gl << 4) ^ ((ni & 7) << 4))) = o;
    }
    __syncthreads();

    // ================= mfma phase: wave w -> tile (w&3), ht-half (w>>2) =======
    {
        int tw = wv & 3;
        int t = Tb + tw;
        if (t < ntiles) {
            int tbase = t << 4;
            char* tile = (char*)&ltile[tw][0];
            const half8* wl = (const half8*)&wlds[0][0][0];
            half8 afrag0 = *(const half8*)(tile + r16 * 128 + ((quad << 4) ^ ((r16 & 7) << 4)));
            half8 afrag1 = *(const half8*)(tile + r16 * 128 + (((quad + 4) << 4) ^ ((r16 & 7) << 4)));
            int htb = (wv >> 2) << 1;                  // 0 or 2
#pragma unroll
            for (int hh = 0; hh < 2; ++hh) {
                int ht = htb + hh;
                f32x4 acc = {biasv[ht], biasv[ht], biasv[ht], biasv[ht]};
                half8 b0 = wl[(ht * 2 + 0) * 64 + lane];   // stride-1 ds_read_b128
                half8 b1 = wl[(ht * 2 + 1) * 64 + lane];
                acc = __builtin_amdgcn_mfma_f32_16x16x32_f16(afrag0, b0, acc, 0, 0, 0);
                acc = __builtin_amdgcn_mfma_f32_16x16x32_f16(afrag1, b1, acc, 0, 0, 0);
#pragma unroll
                for (int r = 0; r < 4; ++r) {
                    int row = tbase + quad * 4 + r;
                    if (row < n) {                     // guards garbage tail rows too
                        float v = fmaxf(acc[r], 0.0f);
                        size_t idx = (size_t)row * HID + ht * 16 + r16;
                        if (out32) out32[idx] = v;
                        if (out16) out16[idx] = __float2half(v);
                    }
                }
            }
        }
    }
}

extern "C" void kernel_launch(void* const* d_in, const int* in_sizes, int n_in,
                              void* d_out, int out_size, void* d_ws, size_t ws_size,
                              hipStream_t stream) {
    const int*   z    = (const int*)d_in[0];
    const float* pos  = (const float*)d_in[1];
    const int*   eidx = (const int*)d_in[2];
    const float* emb  = (const float*)d_in[3];
    const float* Ws   = (const float*)d_in[4];
    const float* bs   = (const float*)d_in[5];
    int n = in_sizes[0];
    int e = in_sizes[2] / 2;
    int nlayers = in_sizes[4] / (HID * HID);
    const int* row = eidx;
    const int* col = eidx + e;
    float* out = (float*)d_out;

    char* ws = (char*)d_ws;
    __half*   X16 = (__half*)ws;                                   // n*64 fp16 (12.8 MB)
    __half*   Y16 = X16 + (size_t)n * HID;                         // n*64 fp16 (ping-pong)
    unsigned* ell = (unsigned*)((char*)Y16 + (size_t)n * HID * 2); // (n+2)*ELLK u32
    int*      cnt = (int*)((char*)ell + (size_t)(n + 2) * ELLK * 4); // n+1 ints
    float4*   pos4 = (float4*)((char*)cnt + (((size_t)(n + 1) * 4 + 15) & ~(size_t)15));

    // 5 dispatches: embed(+cnt zero+pos4), fill, 3x fused layer (wave-specialized)
    // (R16/R29/R30 lessons: cooperative launch doesn't survive graph capture;
    // persistent mega-kernels lose 15x more TLP than the 3 gaps they save.)
    embed_kernel<<<(n * HID / 2 + 255) / 256, 256, 0, stream>>>(z, emb, pos, pos4, X16, cnt, n);
    fill_kernel<<<(e + 255) / 256, 256, 0, stream>>>(row, col, pos4, cnt, ell, e);

    int ntiles = (n + 15) >> 4;
    int lblocks = (ntiles + 3) >> 2;   // 4 tiles/block (8 waves: 8 packs)
    for (int l = 0; l < nlayers; ++l) {
        bool last = (l == nlayers - 1);
        const __half* src = (l & 1) ? Y16 : X16;   // ping-pong: fused kernel reads
        __half*       dst = (l & 1) ? X16 : Y16;   // src everywhere while writing dst
        layer_kernel<<<lblocks, 512, 0, stream>>>(src, cnt, ell,
                                                  Ws + (size_t)l * HID * HID,
                                                  bs + (size_t)l * HID,
                                                  last ? out : nullptr,
                                                  last ? nullptr : dst, n);
    }
}